// Round 2
// baseline (17657.176 us; speedup 1.0000x reference)
//
#include <hip/hip_runtime.h>

// MultiTaskLSTM: B=512, T=1024, I=64, H=256
// R2: 256 blocks = 32 batch-groups x 8 H-slices. Each block owns 32 h-cols
// (=128 gate rows); its W tile (128x320 bf16) lives in REGISTERS (40 VGPR/wave).
// Per step: read full h (16x256 bf16) from L3 via agent atomics, MFMA, gate
// math, publish own 16x32 h-slice, release flag; 8-block group spin-sync.
// Cooperative launch guarantees co-residency for the spin flags.

typedef __attribute__((ext_vector_type(4))) float f32x4;
typedef __attribute__((ext_vector_type(2))) float f32x2;
typedef __attribute__((ext_vector_type(8))) short bf16x8;
typedef __attribute__((ext_vector_type(8))) unsigned short u16x8;

#define T_SZ 1024
#define I_SZ 64
#define H_SZ 256
#define KFRAGS 10          // K=320 / 32
#define MROWS 16
#define NS 8               // H-slice blocks per group
#define NG 32              // batch groups
#define NBLK 256
#define NTHREADS 512
#define AST 328            // A_lds row stride (bf16): 320 + 8 pad
#define A32ST 164
#define GSTL 132           // gates_lds row stride (f32): 128 + 4 pad
#define HROW32 128         // u32 per h row (256 bf16)

#define WT_FRAGS (64 * KFRAGS * 64)        // 40960 frags of 8 bf16 (16B)
#define WS_BIAS_OFF   (WT_FRAGS * 16)      // 655360
#define WS_HBUF_OFF   (WS_BIAS_OFF + 4096) // 659456
#define WS_FLAGS_OFF  (WS_HBUF_OFF + 2 * 512 * 256 * 2)  // 1183744
#define SPIN_CAP (1 << 18)

__device__ __forceinline__ unsigned short f2bf(float f) {
    unsigned int u = __builtin_bit_cast(unsigned int, f);
    unsigned int r = (u + 0x7FFFu + ((u >> 16) & 1u)) >> 16;
    return (unsigned short)r;
}
__device__ __forceinline__ float bf2f(unsigned short s) {
    unsigned int u = ((unsigned int)s) << 16;
    return __builtin_bit_cast(float, u);
}
__device__ __forceinline__ float sigm(float x) {
    return 1.0f / (1.0f + exp2f(-1.44269504f * x));
}
__device__ __forceinline__ float tanhfast(float x) {
    float e = exp2f(2.88539008f * x);   // e^(2x)
    return 1.0f - 2.0f / (e + 1.0f);
}

// Pack W rows for block-slice layout. Global tile gt = ns*8 + nl covers gate
// row g = (nl>>1)*256 + ns*32 + (nl&1)*16 + (lane&15), k = kf*32+(lane>>4)*8+j.
__global__ void prep_kernel(const float* __restrict__ W_ih,
                            const float* __restrict__ W_hh,
                            const float* __restrict__ b_ih,
                            const float* __restrict__ b_hh,
                            unsigned short* __restrict__ Wt,
                            float* __restrict__ bias,
                            int* __restrict__ flags) {
    int gid = blockIdx.x * blockDim.x + threadIdx.x;
    if (gid < WT_FRAGS) {
        int lane = gid & 63;
        int rest = gid >> 6;
        int kf = rest % KFRAGS;
        int gt = rest / KFRAGS;
        int ns = gt >> 3, nl = gt & 7;
        int g  = (nl >> 1) * 256 + ns * 32 + (nl & 1) * 16 + (lane & 15);
        int k0 = kf * 32 + (lane >> 4) * 8;
        u16x8 v;
        #pragma unroll
        for (int j = 0; j < 8; ++j) {
            int k = k0 + j;
            float w = (k < H_SZ) ? W_hh[g * H_SZ + k]
                                 : W_ih[g * I_SZ + (k - H_SZ)];
            v[j] = f2bf(w);
        }
        ((u16x8*)Wt)[gid] = v;
    } else if (gid < WT_FRAGS + 1024) {
        int j = gid - WT_FRAGS;
        bias[j] = b_ih[j] + b_hh[j];
    } else if (gid < WT_FRAGS + 1024 + 256 * 32) {
        flags[gid - WT_FRAGS - 1024] = 0;
    }
}

__global__ __launch_bounds__(NTHREADS)
void lstm_kernel(const float* __restrict__ x,
                 const unsigned short* __restrict__ Wt,
                 const float* __restrict__ bias,
                 unsigned int* __restrict__ hbuf,
                 int* __restrict__ flags,
                 const float* __restrict__ W_dir, const float* __restrict__ b_dir,
                 const float* __restrict__ W_q,   const float* __restrict__ b_q,
                 const float* __restrict__ W_rr,  const float* __restrict__ b_rr,
                 const float* __restrict__ W_sl,  const float* __restrict__ b_sl,
                 float* __restrict__ out)
{
    __shared__ unsigned short A_lds[MROWS * AST];   // [h(256)|x_t(64)] bf16
    __shared__ float gates_lds[MROWS * GSTL];       // local 128 gate cols
    __shared__ float bl[128];

    const int tid  = threadIdx.x;
    const int lane = tid & 63;
    const int wave = tid >> 6;
    const int bid  = blockIdx.x;
    const int ns   = bid >> 5;       // H-slice index
    const int bg   = bid & 31;       // batch group
    const int b0   = bg * MROWS;
    unsigned int* A32 = (unsigned int*)A_lds;

    // ---- register-resident W fragments (this wave's 16 gate cols) ----
    bf16x8 wf[KFRAGS];
    #pragma unroll
    for (int kf = 0; kf < KFRAGS; ++kf)
        wf[kf] = *(const bf16x8*)(Wt +
            ((size_t)((ns * 8 + wave) * KFRAGS + kf) * 64 + lane) * 8);

    if (tid < 128) bl[tid] = bias[(tid >> 5) * 256 + ns * 32 + (tid & 31)];
    for (int i = tid; i < MROWS * HROW32; i += NTHREADS) {
        int r = i >> 7, c = i & 127;
        A32[r * A32ST + c] = 0u;
    }
    float creg = 0.0f;
    const int er = tid >> 5, ejj = tid & 31;   // elementwise (row, h-col)
    __syncthreads();

    const int abyte = (lane & 15) * (AST * 2) + (lane >> 4) * 16;

    for (int t = 0; t < T_SZ; ++t) {
        // ---- x_t load (plain; no coherence needed) ----
        const float* xp = x + (size_t)(b0 + er) * (T_SZ * I_SZ)
                            + (size_t)t * I_SZ + ejj * 2;
        f32x2 xv = *(const f32x2*)xp;

        if (t > 0) {
            // ---- group sync: wave w spins on flag of slice w ----
            if (lane == 0) {
                int* fp = flags + ((bg << 3) + wave) * 32;
                int spin = 0;
                while (__hip_atomic_load(fp, __ATOMIC_RELAXED,
                                         __HIP_MEMORY_SCOPE_AGENT) < t) {
                    if (++spin > SPIN_CAP) break;
                }
            }
            __syncthreads();
            __builtin_amdgcn_fence(__ATOMIC_ACQUIRE, "agent");
            // ---- read h_t (16 rows x 128 u32) ----
            unsigned int* hb = hbuf + (size_t)(t & 1) * (512 * HROW32);
            const int r2 = tid >> 5, c16 = (tid & 31) * 4;
            unsigned int hv0 = __hip_atomic_load(hb + (b0 + r2) * HROW32 + c16 + 0,
                                __ATOMIC_RELAXED, __HIP_MEMORY_SCOPE_AGENT);
            unsigned int hv1 = __hip_atomic_load(hb + (b0 + r2) * HROW32 + c16 + 1,
                                __ATOMIC_RELAXED, __HIP_MEMORY_SCOPE_AGENT);
            unsigned int hv2 = __hip_atomic_load(hb + (b0 + r2) * HROW32 + c16 + 2,
                                __ATOMIC_RELAXED, __HIP_MEMORY_SCOPE_AGENT);
            unsigned int hv3 = __hip_atomic_load(hb + (b0 + r2) * HROW32 + c16 + 3,
                                __ATOMIC_RELAXED, __HIP_MEMORY_SCOPE_AGENT);
            A32[r2 * A32ST + c16 + 0] = hv0;
            A32[r2 * A32ST + c16 + 1] = hv1;
            A32[r2 * A32ST + c16 + 2] = hv2;
            A32[r2 * A32ST + c16 + 3] = hv3;
        }
        // ---- stage x_t (bf16 pair) ----
        A32[er * A32ST + 128 + ejj] =
            (unsigned)f2bf(xv[0]) | ((unsigned)f2bf(xv[1]) << 16);
        __syncthreads();

        // ---- GEMM: 10 MFMAs, W resident ----
        bf16x8 af[KFRAGS];
        #pragma unroll
        for (int kf = 0; kf < KFRAGS; ++kf)
            af[kf] = *(const bf16x8*)((const char*)A_lds + abyte + kf * 64);
        f32x4 acc = {0.0f, 0.0f, 0.0f, 0.0f};
        #pragma unroll
        for (int kf = 0; kf < KFRAGS; ++kf)
            acc = __builtin_amdgcn_mfma_f32_16x16x32_bf16(af[kf], wf[kf], acc, 0, 0, 0);
        const int lc = (wave >> 1) * 32 + (wave & 1) * 16 + (lane & 15);
        const int rb = (lane >> 4) * 4;
        #pragma unroll
        for (int r = 0; r < 4; ++r)
            gates_lds[(rb + r) * GSTL + lc] = acc[r];
        __syncthreads();

        // ---- elementwise: thread owns (er, ejj) ----
        float gi = gates_lds[er * GSTL + ejj]      + bl[ejj];
        float gf = gates_lds[er * GSTL + 32 + ejj] + bl[32 + ejj];
        float gg = gates_lds[er * GSTL + 64 + ejj] + bl[64 + ejj];
        float go = gates_lds[er * GSTL + 96 + ejj] + bl[96 + ejj];
        float ii = sigm(gi), ff = sigm(gf), gG = tanhfast(gg), oo = sigm(go);
        float c = ff * creg + ii * gG;
        creg = c;
        float h = oo * tanhfast(c);

        // ---- publish h slice (pack bf16 pairs via shfl) ----
        unsigned hu = (unsigned)f2bf(h);
        unsigned other = (unsigned)__shfl_xor((int)hu, 1);
        unsigned int* hbw = hbuf + (size_t)((t + 1) & 1) * (512 * HROW32);
        if ((tid & 1) == 0) {
            unsigned v = hu | (other << 16);
            __hip_atomic_store(hbw + (b0 + er) * HROW32 + ns * 16 + (ejj >> 1), v,
                               __ATOMIC_RELAXED, __HIP_MEMORY_SCOPE_AGENT);
        }
        __syncthreads();   // compiler drains vmcnt before s_barrier
        if (tid == 0) {
            __builtin_amdgcn_fence(__ATOMIC_RELEASE, "agent");
            __hip_atomic_store(flags + ((bg << 3) + ns) * 32, t + 1,
                               __ATOMIC_RELAXED, __HIP_MEMORY_SCOPE_AGENT);
        }
    }

    // ---- heads: slice-0 block of each group computes outputs ----
    if (ns == 0) {
        if (lane == 0) {
            int* fp = flags + ((bg << 3) + wave) * 32;
            int spin = 0;
            while (__hip_atomic_load(fp, __ATOMIC_RELAXED,
                                     __HIP_MEMORY_SCOPE_AGENT) < T_SZ) {
                if (++spin > SPIN_CAP) break;
            }
        }
        __syncthreads();
        __builtin_amdgcn_fence(__ATOMIC_ACQUIRE, "agent");
        unsigned int* hb = hbuf + (size_t)(T_SZ & 1) * (512 * HROW32);
        const int r2 = tid >> 5, c16 = (tid & 31) * 4;
        #pragma unroll
        for (int e = 0; e < 4; ++e)
            A32[r2 * A32ST + c16 + e] =
                __hip_atomic_load(hb + (b0 + r2) * HROW32 + c16 + e,
                                  __ATOMIC_RELAXED, __HIP_MEMORY_SCOPE_AGENT);
        __syncthreads();
        if (tid < MROWS * 8) {
            int r = tid >> 3, cc = tid & 7;
            const float* wrow;
            float bb;
            if (cc == 0)      { wrow = W_dir;                 bb = b_dir[0]; }
            else if (cc <= 5) { wrow = W_q + (cc - 1) * H_SZ; bb = b_q[cc - 1]; }
            else if (cc == 6) { wrow = W_rr;                  bb = b_rr[0]; }
            else              { wrow = W_sl;                  bb = b_sl[0]; }
            float s = bb;
            for (int k = 0; k < H_SZ; ++k)
                s += bf2f(A_lds[r * AST + k]) * wrow[k];
            float v = (cc == 0) ? tanhfast(s) : (cc == 7) ? sigm(s) : s;
            out[(b0 + r) * 8 + cc] = v;
        }
    }
}

extern "C" void kernel_launch(void* const* d_in, const int* in_sizes, int n_in,
                              void* d_out, int out_size, void* d_ws, size_t ws_size,
                              hipStream_t stream) {
    const float* x     = (const float*)d_in[0];
    const float* W_ih  = (const float*)d_in[1];
    const float* W_hh  = (const float*)d_in[2];
    const float* b_ih  = (const float*)d_in[3];
    const float* b_hh  = (const float*)d_in[4];
    const float* W_dir = (const float*)d_in[5];
    const float* b_dir = (const float*)d_in[6];
    const float* W_q   = (const float*)d_in[7];
    const float* b_q   = (const float*)d_in[8];
    const float* W_rr  = (const float*)d_in[9];
    const float* b_rr  = (const float*)d_in[10];
    const float* W_sl  = (const float*)d_in[11];
    const float* b_sl  = (const float*)d_in[12];

    unsigned short* Wt   = (unsigned short*)d_ws;
    float* bias          = (float*)((char*)d_ws + WS_BIAS_OFF);
    unsigned int* hbuf   = (unsigned int*)((char*)d_ws + WS_HBUF_OFF);
    int* flags           = (int*)((char*)d_ws + WS_FLAGS_OFF);
    float* outp          = (float*)d_out;

    // 40960 frags + 1024 bias + 8192 flag ints = 50176 = 196 * 256
    prep_kernel<<<196, 256, 0, stream>>>(W_ih, W_hh, b_ih, b_hh, Wt, bias, flags);

    void* args[] = {(void*)&x, (void*)&Wt, (void*)&bias, (void*)&hbuf, (void*)&flags,
                    (void*)&W_dir, (void*)&b_dir, (void*)&W_q, (void*)&b_q,
                    (void*)&W_rr, (void*)&b_rr, (void*)&W_sl, (void*)&b_sl,
                    (void*)&outp};
    hipLaunchCooperativeKernel((void*)lstm_kernel, dim3(NBLK), dim3(NTHREADS),
                               args, 0, stream);
}

// Round 3
// 6149.733 us; speedup vs baseline: 2.8712x; 2.8712x over previous
//
#include <hip/hip_runtime.h>

// MultiTaskLSTM: B=512, T=1024, I=64, H=256
// R3: 256 blocks = 32 batch-groups x 8 H-slices; W register-resident.
// Barrier-free, fence-free t-loop. h exchange via coalesced sc0/sc1
// loads/stores at L3 + per-(group,slice) counting flags (8 waves each add 1).
// Wave owns 16 gate cols = 4 gates x 4 h-cols -> wave-local gate transpose.

typedef __attribute__((ext_vector_type(4))) float f32x4;
typedef __attribute__((ext_vector_type(4))) unsigned int u32x4;
typedef __attribute__((ext_vector_type(8))) short bf16x8;
typedef __attribute__((ext_vector_type(8))) unsigned short u16x8;

#define T_SZ 1024
#define I_SZ 64
#define H_SZ 256
#define KFRAGS 10          // K=320/32 (8 h-frags + 2 x-frags)
#define MROWS 16
#define NTHREADS 512
#define NBLK 256
#define HROW32 128         // u32 per h row (256 bf16)
#define BUFSTRIDE (512 * HROW32)

#define WT_FRAGS (64 * KFRAGS * 64)
#define WS_BIAS_OFF  (WT_FRAGS * 16)
#define WS_HBUF_OFF  (WS_BIAS_OFF + 4096)
#define WS_FLAGS_OFF (WS_HBUF_OFF + 2 * BUFSTRIDE * 4)
#define SPIN_CAP (1 << 20)

__device__ __forceinline__ unsigned short f2bf(float f) {
    unsigned int u = __builtin_bit_cast(unsigned int, f);
    unsigned int r = (u + 0x7FFFu + ((u >> 16) & 1u)) >> 16;
    return (unsigned short)r;
}
__device__ __forceinline__ float bf2f(unsigned short s) {
    unsigned int u = ((unsigned int)s) << 16;
    return __builtin_bit_cast(float, u);
}
__device__ __forceinline__ float sigm(float x) {
    return 1.0f / (1.0f + exp2f(-1.44269504f * x));
}
__device__ __forceinline__ float tanhfast(float x) {
    float e = exp2f(2.88539008f * x);
    return 1.0f - 2.0f / (e + 1.0f);
}

// W pack: tile gt = ns*8 + w; n = lane&15 -> (hcol = n>>2, gate = n&3);
// gate row g = gate*256 + ns*32 + w*4 + hcol; k = kf*32 + (lane>>4)*8 + j.
__global__ void prep_kernel(const float* __restrict__ W_ih,
                            const float* __restrict__ W_hh,
                            const float* __restrict__ b_ih,
                            const float* __restrict__ b_hh,
                            unsigned short* __restrict__ Wt,
                            float* __restrict__ bias,
                            unsigned int* __restrict__ hbuf,
                            int* __restrict__ flags) {
    int gid = blockIdx.x * blockDim.x + threadIdx.x;
    if (gid < WT_FRAGS) {
        int lane = gid & 63;
        int rest = gid >> 6;
        int kf = rest % KFRAGS;
        int gt = rest / KFRAGS;
        int ns = gt >> 3, w = gt & 7;
        int n = lane & 15;
        int g = (n & 3) * 256 + ns * 32 + w * 4 + (n >> 2);
        int k0 = kf * 32 + (lane >> 4) * 8;
        u16x8 v;
        #pragma unroll
        for (int j = 0; j < 8; ++j) {
            int k = k0 + j;
            float wv = (k < H_SZ) ? W_hh[g * H_SZ + k]
                                  : W_ih[g * I_SZ + (k - H_SZ)];
            v[j] = f2bf(wv);
        }
        ((u16x8*)Wt)[gid] = v;
    } else if (gid < WT_FRAGS + 1024) {
        int j = gid - WT_FRAGS;
        bias[j] = b_ih[j] + b_hh[j];
    } else if (gid < WT_FRAGS + 1024 + 2 * BUFSTRIDE) {
        hbuf[gid - WT_FRAGS - 1024] = 0u;
    } else if (gid < WT_FRAGS + 1024 + 2 * BUFSTRIDE + 8192) {
        flags[gid - WT_FRAGS - 1024 - 2 * BUFSTRIDE] = 0;
    }
}

__global__ __launch_bounds__(NTHREADS)
void lstm_kernel(const float* __restrict__ x,
                 const unsigned short* __restrict__ Wt,
                 const float* __restrict__ bias,
                 unsigned int* __restrict__ hbuf,
                 int* __restrict__ flags,
                 const float* __restrict__ W_dir, const float* __restrict__ b_dir,
                 const float* __restrict__ W_q,   const float* __restrict__ b_q,
                 const float* __restrict__ W_rr,  const float* __restrict__ b_rr,
                 const float* __restrict__ W_sl,  const float* __restrict__ b_sl,
                 float* __restrict__ out)
{
    __shared__ float tr[8 * 16 * 17];       // wave-private gate transpose
    __shared__ unsigned int hstage[MROWS * HROW32];  // heads staging

    const int tid  = threadIdx.x;
    const int lane = tid & 63;
    const int wave = tid >> 6;
    const int ns   = blockIdx.x >> 5;
    const int bg   = blockIdx.x & 31;
    const int b0   = bg * MROWS;

    // register-resident W fragments
    bf16x8 wf[KFRAGS];
    #pragma unroll
    for (int kf = 0; kf < KFRAGS; ++kf)
        wf[kf] = *(const bf16x8*)(Wt +
            ((size_t)((ns * 8 + wave) * KFRAGS + kf) * 64 + lane) * 8);

    const int er = lane & 15;          // batch row (frag + elementwise)
    const int hc = lane >> 4;          // 0..3: elementwise h-col group
    const int jg = ns * 32 + wave * 4 + hc;   // global h col
    const float bi0 = bias[jg];
    const float bi1 = bias[256 + jg];
    const float bi2 = bias[512 + jg];
    const float bi3 = bias[768 + jg];

    float* trw = &tr[wave * (16 * 17)];
    const int n_idx = lane & 15;
    const int rb = (lane >> 4) * 4;

    const float* xbase = x + (size_t)(b0 + er) * (T_SZ * I_SZ) + hc * 8;
    int* myflag = flags + ((bg << 3) + ns) * 32;

    float creg = 0.0f;

    for (int t = 0; t < T_SZ; ++t) {
        const unsigned int* hb = hbuf + (size_t)(t & 1) * BUFSTRIDE;
        unsigned int* hbw = hbuf + (size_t)((t + 1) & 1) * BUFSTRIDE;

        // ---- x fragments (normal cached loads + pk-convert) ----
        const float* xp = xbase + (size_t)t * I_SZ;
        f32x4 xa = *(const f32x4*)xp;
        f32x4 xb = *(const f32x4*)(xp + 4);
        f32x4 xc = *(const f32x4*)(xp + 32);
        f32x4 xd = *(const f32x4*)(xp + 36);
        unsigned p0, p1, p2, p3, p4, p5, p6, p7;
        asm("v_cvt_pk_bf16_f32 %0, %1, %2" : "=v"(p0) : "v"(xa[0]), "v"(xa[1]));
        asm("v_cvt_pk_bf16_f32 %0, %1, %2" : "=v"(p1) : "v"(xa[2]), "v"(xa[3]));
        asm("v_cvt_pk_bf16_f32 %0, %1, %2" : "=v"(p2) : "v"(xb[0]), "v"(xb[1]));
        asm("v_cvt_pk_bf16_f32 %0, %1, %2" : "=v"(p3) : "v"(xb[2]), "v"(xb[3]));
        asm("v_cvt_pk_bf16_f32 %0, %1, %2" : "=v"(p4) : "v"(xc[0]), "v"(xc[1]));
        asm("v_cvt_pk_bf16_f32 %0, %1, %2" : "=v"(p5) : "v"(xc[2]), "v"(xc[3]));
        asm("v_cvt_pk_bf16_f32 %0, %1, %2" : "=v"(p6) : "v"(xd[0]), "v"(xd[1]));
        asm("v_cvt_pk_bf16_f32 %0, %1, %2" : "=v"(p7) : "v"(xd[2]), "v"(xd[3]));
        u32x4 xf0u = {p0, p1, p2, p3};
        u32x4 xf1u = {p4, p5, p6, p7};

        // ---- wait for h_t of all 8 slices ----
        if (t) {
            const int target = 8 * t;
            #pragma unroll
            for (int s = 0; s < 8; ++s) {
                const int* fp = flags + ((bg << 3) + s) * 32;
                int fv, spin = 0;
                do {
                    fv = __hip_atomic_load(fp, __ATOMIC_RELAXED,
                                           __HIP_MEMORY_SCOPE_AGENT);
                } while (fv < target && ++spin < SPIN_CAP);
            }
        }

        // ---- h fragments: coalesced sc0/sc1 dwordx4 (bypass L1/L2) ----
        u32x4 hv0, hv1, hv2, hv3, hv4, hv5, hv6, hv7;
        {
            const unsigned int* hp = hb + (size_t)(b0 + er) * HROW32 + hc * 4;
            asm volatile("global_load_dwordx4 %0, %1, off sc0 sc1" : "=v"(hv0) : "v"(hp) : "memory");
            asm volatile("global_load_dwordx4 %0, %1, off sc0 sc1" : "=v"(hv1) : "v"(hp + 16) : "memory");
            asm volatile("global_load_dwordx4 %0, %1, off sc0 sc1" : "=v"(hv2) : "v"(hp + 32) : "memory");
            asm volatile("global_load_dwordx4 %0, %1, off sc0 sc1" : "=v"(hv3) : "v"(hp + 48) : "memory");
            asm volatile("global_load_dwordx4 %0, %1, off sc0 sc1" : "=v"(hv4) : "v"(hp + 64) : "memory");
            asm volatile("global_load_dwordx4 %0, %1, off sc0 sc1" : "=v"(hv5) : "v"(hp + 80) : "memory");
            asm volatile("global_load_dwordx4 %0, %1, off sc0 sc1" : "=v"(hv6) : "v"(hp + 96) : "memory");
            asm volatile("global_load_dwordx4 %0, %1, off sc0 sc1" : "=v"(hv7) : "v"(hp + 112) : "memory");
        }
        asm volatile("s_waitcnt vmcnt(0)" ::: "memory");
        __builtin_amdgcn_sched_barrier(0);

        // ---- 10 MFMAs ----
        f32x4 acc = {0.0f, 0.0f, 0.0f, 0.0f};
        acc = __builtin_amdgcn_mfma_f32_16x16x32_bf16(__builtin_bit_cast(bf16x8, hv0), wf[0], acc, 0, 0, 0);
        acc = __builtin_amdgcn_mfma_f32_16x16x32_bf16(__builtin_bit_cast(bf16x8, hv1), wf[1], acc, 0, 0, 0);
        acc = __builtin_amdgcn_mfma_f32_16x16x32_bf16(__builtin_bit_cast(bf16x8, hv2), wf[2], acc, 0, 0, 0);
        acc = __builtin_amdgcn_mfma_f32_16x16x32_bf16(__builtin_bit_cast(bf16x8, hv3), wf[3], acc, 0, 0, 0);
        acc = __builtin_amdgcn_mfma_f32_16x16x32_bf16(__builtin_bit_cast(bf16x8, hv4), wf[4], acc, 0, 0, 0);
        acc = __builtin_amdgcn_mfma_f32_16x16x32_bf16(__builtin_bit_cast(bf16x8, hv5), wf[5], acc, 0, 0, 0);
        acc = __builtin_amdgcn_mfma_f32_16x16x32_bf16(__builtin_bit_cast(bf16x8, hv6), wf[6], acc, 0, 0, 0);
        acc = __builtin_amdgcn_mfma_f32_16x16x32_bf16(__builtin_bit_cast(bf16x8, hv7), wf[7], acc, 0, 0, 0);
        acc = __builtin_amdgcn_mfma_f32_16x16x32_bf16(__builtin_bit_cast(bf16x8, xf0u), wf[8], acc, 0, 0, 0);
        acc = __builtin_amdgcn_mfma_f32_16x16x32_bf16(__builtin_bit_cast(bf16x8, xf1u), wf[9], acc, 0, 0, 0);

        // ---- wave-local 16x16 gate transpose (no barrier) ----
        #pragma unroll
        for (int q = 0; q < 4; ++q)
            trw[(rb + q) * 17 + n_idx] = acc[q];
        float gi = trw[er * 17 + hc * 4 + 0] + bi0;
        float gf = trw[er * 17 + hc * 4 + 1] + bi1;
        float gg = trw[er * 17 + hc * 4 + 2] + bi2;
        float go = trw[er * 17 + hc * 4 + 3] + bi3;

        float ii = sigm(gi), ff = sigm(gf), gG = tanhfast(gg), oo = sigm(go);
        float c = ff * creg + ii * gG;
        creg = c;
        float h = oo * tanhfast(c);

        // ---- publish h slice: pack bf16 pairs, sc0/sc1 store ----
        unsigned hu = (unsigned)f2bf(h);
        unsigned pj = (unsigned)__shfl_xor((int)hu, 16);
        if (!(lane & 16)) {
            unsigned v = hu | (pj << 16);
            unsigned int* sp = hbw + (size_t)(b0 + er) * HROW32
                               + ns * 16 + wave * 2 + (hc >> 1);
            asm volatile("global_store_dword %0, %1, off sc0 sc1" :: "v"(sp), "v"(v) : "memory");
        }
        asm volatile("s_waitcnt vmcnt(0)" ::: "memory");
        if (lane == 0)
            __hip_atomic_fetch_add(myflag, 1, __ATOMIC_RELAXED,
                                   __HIP_MEMORY_SCOPE_AGENT);
    }

    // ---- heads (slice-0 blocks) ----
    if (ns == 0) {
        {
            const int target = 8 * T_SZ;
            #pragma unroll
            for (int s = 0; s < 8; ++s) {
                const int* fp = flags + ((bg << 3) + s) * 32;
                int fv, spin = 0;
                do {
                    fv = __hip_atomic_load(fp, __ATOMIC_RELAXED,
                                           __HIP_MEMORY_SCOPE_AGENT);
                } while (fv < target && ++spin < SPIN_CAP);
            }
        }
        // h_T lives in buf[T_SZ & 1] = buf0
        {
            int r = tid >> 5, c4 = (tid & 31) * 4;
            const unsigned int* hp = hbuf + (size_t)(b0 + r) * HROW32 + c4;
            u32x4 hv;
            asm volatile("global_load_dwordx4 %0, %1, off sc0 sc1" : "=v"(hv) : "v"(hp) : "memory");
            asm volatile("s_waitcnt vmcnt(0)" ::: "memory");
            __builtin_amdgcn_sched_barrier(0);
            hstage[r * HROW32 + c4 + 0] = hv[0];
            hstage[r * HROW32 + c4 + 1] = hv[1];
            hstage[r * HROW32 + c4 + 2] = hv[2];
            hstage[r * HROW32 + c4 + 3] = hv[3];
        }
        __syncthreads();
        if (tid < MROWS * 8) {
            int r = tid >> 3, cc = tid & 7;
            const float* wrow;
            float bb;
            if (cc == 0)      { wrow = W_dir;                 bb = b_dir[0]; }
            else if (cc <= 5) { wrow = W_q + (cc - 1) * H_SZ; bb = b_q[cc - 1]; }
            else if (cc == 6) { wrow = W_rr;                  bb = b_rr[0]; }
            else              { wrow = W_sl;                  bb = b_sl[0]; }
            float s = bb;
            for (int k = 0; k < H_SZ; ++k) {
                unsigned u = hstage[r * HROW32 + (k >> 1)];
                unsigned short hs = (k & 1) ? (unsigned short)(u >> 16)
                                            : (unsigned short)(u & 0xFFFF);
                s += bf2f(hs) * wrow[k];
            }
            float v = (cc == 0) ? tanhfast(s) : (cc == 7) ? sigm(s) : s;
            out[(b0 + r) * 8 + cc] = v;
        }
    }
}

extern "C" void kernel_launch(void* const* d_in, const int* in_sizes, int n_in,
                              void* d_out, int out_size, void* d_ws, size_t ws_size,
                              hipStream_t stream) {
    const float* x     = (const float*)d_in[0];
    const float* W_ih  = (const float*)d_in[1];
    const float* W_hh  = (const float*)d_in[2];
    const float* b_ih  = (const float*)d_in[3];
    const float* b_hh  = (const float*)d_in[4];
    const float* W_dir = (const float*)d_in[5];
    const float* b_dir = (const float*)d_in[6];
    const float* W_q   = (const float*)d_in[7];
    const float* b_q   = (const float*)d_in[8];
    const float* W_rr  = (const float*)d_in[9];
    const float* b_rr  = (const float*)d_in[10];
    const float* W_sl  = (const float*)d_in[11];
    const float* b_sl  = (const float*)d_in[12];

    unsigned short* Wt = (unsigned short*)d_ws;
    float* bias        = (float*)((char*)d_ws + WS_BIAS_OFF);
    unsigned int* hbuf = (unsigned int*)((char*)d_ws + WS_HBUF_OFF);
    int* flags         = (int*)((char*)d_ws + WS_FLAGS_OFF);
    float* outp        = (float*)d_out;

    // 40960 frags + 1024 bias + 131072 hbuf + 8192 flags = 181248 = 708*256
    prep_kernel<<<708, 256, 0, stream>>>(W_ih, W_hh, b_ih, b_hh, Wt, bias,
                                         hbuf, flags);

    void* args[] = {(void*)&x, (void*)&Wt, (void*)&bias, (void*)&hbuf,
                    (void*)&flags, (void*)&W_dir, (void*)&b_dir, (void*)&W_q,
                    (void*)&b_q, (void*)&W_rr, (void*)&b_rr, (void*)&W_sl,
                    (void*)&b_sl, (void*)&outp};
    hipLaunchCooperativeKernel((void*)lstm_kernel, dim3(NBLK), dim3(NTHREADS),
                               args, 0, stream);
}